// Round 8
// baseline (847.830 us; speedup 1.0000x reference)
//
#include <hip/hip_runtime.h>

// ---------------------------------------------------------------------------
// SDTA block on MI355X.  B=16, C=384, H=W=56, N=3136, T=B*N=50176, NH=8, HD=48
// XCA trick: S = Wq^T (Y^T Y) Wk  -> compute G=Y^T Y per batch (384x384), then
// P = Wqk^T G, S_h = Pq_h @ Wk_h, norms = diag(P . Wqk).
// MLP mid: UNFUSED two half-T passes through h2 (fused variants measured
// slower; see round 4-6 notes).
// gemmx v2: double-buffered LDS + counted vmcnt (T4).  The old loop's
// __syncthreads drained vmcnt(0) every k-step, serially exposing ~900cy HBM
// latency x 12 steps at ~1 block/CU residency.  Now the next tile's 4 loads
// stay in flight across the barriers (vmcnt(4), never 0 mid-loop).
// Workspace peak: 235,094,016 B (224.2 MiB) — lifetime-aliased regions.
// ---------------------------------------------------------------------------

typedef __attribute__((ext_vector_type(8))) short short8;
typedef __attribute__((ext_vector_type(4))) float floatx4;

#define NB 16
#define DIM 384
#define NTOK 3136
#define TTOK 50176   // NB*NTOK
#define NH 8
#define HD 48

__device__ __forceinline__ unsigned short f2bf(float f) {
  union { float f; unsigned int u; } v; v.f = f;
  unsigned int u = v.u;
  unsigned int r = (u + 0x7FFFu + ((u >> 16) & 1u)) >> 16;  // RNE
  return (unsigned short)r;
}
__device__ __forceinline__ float bf2f(unsigned short h) {
  union { unsigned int u; float f; } v; v.u = ((unsigned int)h) << 16;
  return v.f;
}

// async global->LDS, 16B per lane; LDS dest is wave-uniform base + lane*16.
__device__ __forceinline__ void gload_lds16(const unsigned short* g, unsigned short* l) {
  __builtin_amdgcn_global_load_lds(
      (const __attribute__((address_space(1))) unsigned int*)g,
      (__attribute__((address_space(3))) unsigned int*)l, 16, 0, 0);
}

// ---------------------------------------------------------------------------
// Weight transpose + bf16 convert:  wt[n*K+k] = bf16(w[k*N+n])
// ---------------------------------------------------------------------------
__global__ void wtrans(const float* __restrict__ w, unsigned short* __restrict__ wt,
                       int K, int N) {
  int g = blockIdx.x * 256 + threadIdx.x;
  if (g < K * N) {
    int k = g / N, n = g % N;
    wt[(size_t)n * K + k] = f2bf(w[g]);
  }
}

// ---------------------------------------------------------------------------
// Depthwise 3x3 conv, SAME, with two-source add: dst = conv(a+b) + bias
// ---------------------------------------------------------------------------
__global__ void dwconv(const float* __restrict__ a, long bsA,
                       const float* __restrict__ b2, long bsB,
                       const float* __restrict__ w, const float* __restrict__ bias,
                       float* __restrict__ dst) {
  int g = blockIdx.x * 256 + threadIdx.x;   // < 16*128*3136
  int xx = g % 56;
  int yy = (g / 56) % 56;
  int c  = (g / NTOK) % 128;
  int b  = g / (NTOK * 128);
  const float* pa = a  + (size_t)b * bsA + (size_t)c * NTOK;
  const float* pb = b2 + (size_t)b * bsB + (size_t)c * NTOK;
  float acc = bias[c];
  #pragma unroll
  for (int ky = 0; ky < 3; ky++) {
    int y2 = yy + ky - 1;
    if (y2 < 0 || y2 >= 56) continue;
    #pragma unroll
    for (int kx = 0; kx < 3; kx++) {
      int x2 = xx + kx - 1;
      if (x2 < 0 || x2 >= 56) continue;
      acc += w[c * 9 + ky * 3 + kx] * (pa[y2 * 56 + x2] + pb[y2 * 56 + x2]);
    }
  }
  dst[((size_t)b * 128 + c) * NTOK + yy * 56 + xx] = acc;
}

// ---------------------------------------------------------------------------
// build_ln1 (tiled): gather NCHW pieces for 32 tokens into a [384][33] fp32
// LDS tile, per-token LN, write x_flat fp32 [T,384], y bf16 [T,384], and
// yT bf16 [B,384,3136] (channel-major, for the G = Y^T Y gemm).
// ---------------------------------------------------------------------------
__global__ __launch_bounds__(256) void build_ln1(
    const float* __restrict__ x, const float* __restrict__ s1,
    const float* __restrict__ s2, const float* __restrict__ g,
    const float* __restrict__ bb, float* __restrict__ xflat,
    unsigned short* __restrict__ y, unsigned short* __restrict__ yT) {
  __shared__ float tile[384 * 33];
  __shared__ float psum[8][32], psumsq[8][32];
  __shared__ float smean[32], srs[32];
  int blk = blockIdx.x;
  int b = blk / 98, n0 = (blk % 98) * 32;
  int t = threadIdx.x;
  int nl = t & 31, crow = t >> 5;        // staging: lane->n (coalesced), 8 c-rows/iter

  #pragma unroll 4
  for (int i = 0; i < 48; i++) {
    int c = i * 8 + crow;
    float v;
    if (c < 128)      v = x[((size_t)b * DIM + c) * NTOK + n0 + nl];
    else if (c < 256) v = s1[((size_t)b * 128 + (c - 128)) * NTOK + n0 + nl];
    else              v = s2[((size_t)b * 128 + (c - 256)) * NTOK + n0 + nl];
    tile[c * 33 + nl] = v;
  }
  __syncthreads();

  // per-token partial sums: 8 segments of 48 channels
  {
    int seg = t >> 5, tok = t & 31;
    float s = 0.f, sq = 0.f;
    #pragma unroll 8
    for (int cc = 0; cc < 48; cc++) {
      float v = tile[(seg * 48 + cc) * 33 + tok];
      s += v; sq += v * v;
    }
    psum[seg][tok] = s; psumsq[seg][tok] = sq;
  }
  __syncthreads();
  if (t < 32) {
    float s = 0.f, sq = 0.f;
    #pragma unroll
    for (int seg = 0; seg < 8; seg++) { s += psum[seg][t]; sq += psumsq[seg][t]; }
    float mean = s * (1.f / DIM);
    float var = sq * (1.f / DIM) - mean * mean;
    smean[t] = mean;
    srs[t] = rsqrtf(var + 1e-6f);
  }
  __syncthreads();

  // output: coalesced rows of x_flat / y; overwrite tile with normalized vals
  #pragma unroll 4
  for (int i = 0; i < 48; i++) {
    int idx = i * 256 + t;               // < 12288 = 32*384
    int tok = idx / 384, c = idx - tok * 384;
    float v = tile[c * 33 + tok];
    float vn = (v - smean[tok]) * srs[tok] * g[c] + bb[c];
    size_t o = (size_t)(b * NTOK + n0 + tok) * DIM + c;
    xflat[o] = v;
    y[o] = f2bf(vn);
    tile[c * 33 + tok] = vn;             // slot (c,tok) touched by this thread only
  }
  __syncthreads();
  // transposed write: yT[b][c][n]
  #pragma unroll 4
  for (int i = 0; i < 48; i++) {
    int idx = i * 256 + t;
    int c = idx >> 5, tok = idx & 31;
    yT[((size_t)b * DIM + c) * NTOK + n0 + tok] = f2bf(tile[c * 33 + tok]);
  }
}

// ---------------------------------------------------------------------------
// Plain rowwise LN: fp32 [T,384] -> bf16 [T,384]
// ---------------------------------------------------------------------------
__global__ __launch_bounds__(256) void ln_rows(
    const float* __restrict__ in, const float* __restrict__ g,
    const float* __restrict__ bb, unsigned short* __restrict__ out) {
  int tkn = blockIdx.x * 4 + (threadIdx.x >> 6);
  int lane = threadIdx.x & 63;
  const float* row = in + (size_t)tkn * DIM;
  float v[6];
  float s = 0.f, sq = 0.f;
  #pragma unroll
  for (int i = 0; i < 6; i++) {
    int c = lane + i * 64;
    v[i] = row[c]; s += v[i]; sq += v[i] * v[i];
  }
  #pragma unroll
  for (int off = 32; off; off >>= 1) {
    s += __shfl_xor(s, off);
    sq += __shfl_xor(sq, off);
  }
  float mean = s * (1.f / DIM);
  float var = sq * (1.f / DIM) - mean * mean;
  float rs = rsqrtf(var + 1e-6f);
  #pragma unroll
  for (int i = 0; i < 6; i++) {
    int c = lane + i * 64;
    out[(size_t)tkn * DIM + c] = f2bf((v[i] - mean) * rs * g[c] + bb[c]);
  }
}

// ---------------------------------------------------------------------------
// 128-tile MFMA GEMM, double-buffered with counted vmcnt (T4):
// C[M,N] = A[M,K] @ Bt[N,K]^T, bf16 in.
// MODE 0: bf16 out | MODE 1: +bias, exact GELU, bf16 | MODE 2: +bias+resid fp32
// MODE 3: plain fp32 out.
// Pipeline: stage(k+1) is issued BEFORE waiting on stage(k); the wait is a
// counted vmcnt(4/3) (= loads of k+1 still in flight), never 0 mid-loop, so
// HBM latency overlaps the previous step's compute + barrier.  Barriers are
// lgkmcnt-only + raw s_barrier.  Hazards: trailing barrier of step k-1
// retires all ds_reads of the buffer step k stages into; leading vmcnt(L) +
// barrier proves the current buffer's loads landed (vmcnt counts
// global_load_lds completion).
// ---------------------------------------------------------------------------
template<int BN, int MODE>
__global__ __launch_bounds__(256) void gemmx(
    const unsigned short* __restrict__ A, const unsigned short* __restrict__ Bt,
    const float* __restrict__ bias, const float* __restrict__ resid,
    void* __restrict__ out, int M, int N, int K, int lda, int ldb,
    int nsplit, long aBatch, long aSplit, long bBatch, long bSplit, long cBatch) {
  constexpr int MT = (BN == 128) ? 4 : 2;
  constexpr int NT = 4;
  __shared__ __align__(16) unsigned short As[2][128 * 32];
  __shared__ __align__(16) unsigned short Bs[2][BN * 32];
  const int tid = threadIdx.x;
  const int w = tid >> 6, lane = tid & 63;
  const int quad = lane >> 4, r16 = lane & 15;

  // bijective XCD swizzle over (x,y)
  const int nwg = gridDim.x * gridDim.y;
  const int bid = blockIdx.y * gridDim.x + blockIdx.x;
  const int q8 = nwg >> 3, r8 = nwg & 7;
  const int xcd = bid & 7, loc = bid >> 3;
  const int swz = (xcd < r8 ? xcd * (q8 + 1) : r8 * (q8 + 1) + (xcd - r8) * q8) + loc;
  const int bx = swz % gridDim.x, by = swz / gridDim.x;
  const int row0 = by * 128, col0 = bx * BN;

  const int z = blockIdx.z;
  const int bz = z / nsplit, sz = z - bz * nsplit;
  A  += bz * aBatch + sz * aSplit;
  Bt += bz * bBatch + sz * bSplit;
  const size_t cOff = (size_t)z * cBatch;

  const int wm = (BN == 128) ? (w >> 1) * 64 : w * 32;
  const int wn = (BN == 128) ? (w & 1) * 64 : 0;
  const int lrow = lane >> 2;
  const int lcol = (lane & 3) * 8;

  const unsigned short* aP0 = A + (size_t)(row0 + w * 32 + lrow) * lda + lcol;
  const unsigned short* aP1 = aP0 + (size_t)16 * lda;
  const unsigned short* bP0 = Bt + (size_t)(col0 + ((BN == 128) ? w * 32 : w * 16) + lrow) * ldb + lcol;
  const unsigned short* bP1 = bP0 + (size_t)16 * ldb;

  const int nk = K >> 5;

  // prologue: stage k-step 0 into buffer 0
  gload_lds16(aP0, &As[0][(2 * w) * 512]);
  gload_lds16(aP1, &As[0][(2 * w + 1) * 512]);
  if (BN == 128) {
    gload_lds16(bP0, &Bs[0][(2 * w) * 512]);
    gload_lds16(bP1, &Bs[0][(2 * w + 1) * 512]);
  } else {
    gload_lds16(bP0, &Bs[0][w * 512]);
  }

  floatx4 acc[MT][NT] = {};

  for (int ki = 0; ki < nk; ki++) {
    const int cur = ki & 1;
    if (ki + 1 < nk) {
      // issue next tile's loads into the other buffer (safe: last reads of
      // that buffer retired at the trailing barrier of iteration ki-1)
      const int kn = (ki + 1) * 32;
      gload_lds16(aP0 + kn, &As[cur ^ 1][(2 * w) * 512]);
      gload_lds16(aP1 + kn, &As[cur ^ 1][(2 * w + 1) * 512]);
      if (BN == 128) {
        gload_lds16(bP0 + kn, &Bs[cur ^ 1][(2 * w) * 512]);
        gload_lds16(bP1 + kn, &Bs[cur ^ 1][(2 * w + 1) * 512]);
      } else {
        gload_lds16(bP0 + kn, &Bs[cur ^ 1][w * 512]);
      }
      // wait only for cur's loads; the 4 (3) just-issued stay in flight
      if (BN == 128) asm volatile("s_waitcnt vmcnt(4)" ::: "memory");
      else           asm volatile("s_waitcnt vmcnt(3)" ::: "memory");
    } else {
      asm volatile("s_waitcnt vmcnt(0)" ::: "memory");
    }
    __builtin_amdgcn_s_barrier();

    short8 af[MT], bfr[NT];
    #pragma unroll
    for (int mi = 0; mi < MT; mi++)
      af[mi] = *(const short8*)(&As[cur][(wm + mi * 16 + r16) * 32 + quad * 8]);
    #pragma unroll
    for (int ni = 0; ni < NT; ni++)
      bfr[ni] = *(const short8*)(&Bs[cur][(wn + ni * 16 + r16) * 32 + quad * 8]);
    #pragma unroll
    for (int mi = 0; mi < MT; mi++)
      #pragma unroll
      for (int ni = 0; ni < NT; ni++)
        acc[mi][ni] = __builtin_amdgcn_mfma_f32_16x16x32_bf16(af[mi], bfr[ni], acc[mi][ni], 0, 0, 0);

    // retire this iteration's ds_reads before anyone overwrites buf[cur]
    asm volatile("s_waitcnt lgkmcnt(0)" ::: "memory");
    __builtin_amdgcn_s_barrier();
  }

  #pragma unroll
  for (int mi = 0; mi < MT; mi++)
    #pragma unroll
    for (int ni = 0; ni < NT; ni++)
      #pragma unroll
      for (int p = 0; p < 4; p++) {
        int row = row0 + wm + mi * 16 + quad * 4 + p;
        int col = col0 + wn + ni * 16 + r16;
        size_t idx = (size_t)row * N + col;
        float v = acc[mi][ni][p];
        if (MODE == 0) {
          ((unsigned short*)out)[cOff + idx] = f2bf(v);
        } else if (MODE == 1) {
          v += bias[col];
          v = 0.5f * v * (1.0f + erff(v * 0.70710678118654752f));
          ((unsigned short*)out)[idx] = f2bf(v);
        } else if (MODE == 2) {
          v += bias[col] + resid[idx];
          ((float*)out)[idx] = v;
        } else {
          ((float*)out)[cOff + idx] = v;
        }
      }
}

// ---------------------------------------------------------------------------
// Sum the 7 K-split G partial slabs (bf16) -> Gbf [16][384*384] bf16.
// ---------------------------------------------------------------------------
__global__ __launch_bounds__(256) void gsum(const unsigned short* __restrict__ Gp,
                                            unsigned short* __restrict__ Gbf) {
  int b = blockIdx.x / 576;                         // 576 blocks per batch
  int i = (blockIdx.x % 576) * 256 + threadIdx.x;   // < 147456
  float s = 0.f;
  #pragma unroll
  for (int p = 0; p < 7; p++)
    s += bf2f(Gp[((size_t)(b * 7 + p)) * 147456 + i]);
  Gbf[(size_t)b * 147456 + i] = f2bf(s);
}

// ---------------------------------------------------------------------------
// attn_finish2: per (b,h) block.  P = Wqk^T G  ([768][384] fp32 per b).
//   S[d][e]  = sum_c Pq[h*48+d][c] * Wk[c][h*48+e]   (Wk staged bf16 from qkvT)
//   nq[d]    = sum_c Pq[h*48+d][c] * Wq[c][h*48+d]   (fp32 qkv_w column)
//   nk[e]    = sum_c Pk[384+h*48+e][c] * Wk[c][h*48+e]
// then row softmax of S/(qn*kn) -> attnb[bh][48][48].
// ---------------------------------------------------------------------------
__global__ __launch_bounds__(256) void attn_finish2(
    const float* __restrict__ P, const unsigned short* __restrict__ qkvT,
    const float* __restrict__ qkv_w, float* __restrict__ attnb) {
  __shared__ unsigned short wkT[48 * 392];   // wkT[e][c] bf16
  __shared__ float Ss[48 * 49];
  __shared__ float qn[48], kn[48];
  int bh = blockIdx.x, b = bh >> 3, h = bh & 7;
  int t = threadIdx.x;
  const float* Pb = P + (size_t)b * 294912;

  // stage Wk_h^T rows (qkvT rows 384+h*48 .. +48, each 384 bf16)
  #pragma unroll
  for (int i = 0; i < 9; i++) {
    int idx = t + i * 256;                   // < 2304 = 48 rows * 48 chunks
    int e = idx / 48, j = idx - e * 48;
    *(short8*)(&wkT[e * 392 + j * 8]) =
        *(const short8*)(&qkvT[(size_t)(384 + h * 48 + e) * 384 + j * 8]);
  }
  // norms (waves 0 and 1 partial-idle; cheap)
  if (t < 48) {
    const float* pr = Pb + (size_t)(h * 48 + t) * 384;
    const float* wc = qkv_w + h * 48 + t;
    float s = 0.f;
    #pragma unroll 8
    for (int c = 0; c < 384; c++) s += pr[c] * wc[(size_t)c * 1152];
    qn[t] = fmaxf(sqrtf(fmaxf(s, 0.f)), 1e-12f);
  } else if (t >= 64 && t < 112) {
    int e = t - 64;
    const float* pr = Pb + (size_t)(384 + h * 48 + e) * 384;
    const float* wc = qkv_w + 384 + h * 48 + e;
    float s = 0.f;
    #pragma unroll 8
    for (int c = 0; c < 384; c++) s += pr[c] * wc[(size_t)c * 1152];
    kn[e] = fmaxf(sqrtf(fmaxf(s, 0.f)), 1e-12f);
  }
  __syncthreads();

  // S: thread owns 3x3 of the 48x48 output
  int d0 = (t >> 4) * 3, e0 = (t & 15) * 3;
  float acc[3][3] = {};
  const float* pq0 = Pb + (size_t)(h * 48 + d0) * 384;
  for (int c8 = 0; c8 < 48; c8++) {
    floatx4 pv[3][2];
    #pragma unroll
    for (int i = 0; i < 3; i++) {
      pv[i][0] = *(const floatx4*)(pq0 + (size_t)i * 384 + c8 * 8);
      pv[i][1] = *(const floatx4*)(pq0 + (size_t)i * 384 + c8 * 8 + 4);
    }
    #pragma unroll
    for (int j = 0; j < 3; j++) {
      short8 wv = *(const short8*)(&wkT[(e0 + j) * 392 + c8 * 8]);
      #pragma unroll
      for (int kk = 0; kk < 4; kk++) {
        float wa = bf2f((unsigned short)wv[kk]);
        float wb = bf2f((unsigned short)wv[4 + kk]);
        #pragma unroll
        for (int i = 0; i < 3; i++)
          acc[i][j] += pv[i][0][kk] * wa + pv[i][1][kk] * wb;
      }
    }
  }
  #pragma unroll
  for (int i = 0; i < 3; i++)
    #pragma unroll
    for (int j = 0; j < 3; j++)
      Ss[(d0 + i) * 49 + e0 + j] = acc[i][j] / (qn[d0 + i] * kn[e0 + j]);
  __syncthreads();

  if (t < 48) {
    float m = -1e30f;
    for (int e = 0; e < 48; e++) m = fmaxf(m, Ss[t * 49 + e]);
    float ssum = 0.f;
    float ex[48];
    for (int e = 0; e < 48; e++) { ex[e] = expf(Ss[t * 49 + e] - m); ssum += ex[e]; }
    float inv = 1.f / ssum;
    float* op = attnb + (size_t)bh * 2304 + t * 48;
    for (int e = 0; e < 48; e++) op[e] = ex[e] * inv;
  }
}

// ---------------------------------------------------------------------------
// y_attn[b,n,h*48+d] = sum_e attn[b,h,d,e] * v[b,n,h,e]   -> bf16
// 6272 blocks = (b,h,chunk-of-64).  V comes from vbf [T,384] bf16.
// ---------------------------------------------------------------------------
__global__ __launch_bounds__(256) void attn_apply(
    const unsigned short* __restrict__ vbf, const float* __restrict__ attnb,
    unsigned short* __restrict__ yat) {
  __shared__ float at[48 * 52];
  __shared__ float vs[64 * 56];
  int bh = blockIdx.x / 49, chunk = blockIdx.x % 49;
  int b = bh >> 3, h = bh & 7;
  int t = threadIdx.x;
  int lane = t & 63, w = t >> 6;
  #pragma unroll
  for (int i = 0; i < 9; i++) {
    int idx = t + i * 256;
    if (idx < 2304) at[(idx / 48) * 52 + idx % 48] = attnb[(size_t)bh * 2304 + idx];
  }
  #pragma unroll
  for (int i = 0; i < 2; i++) {
    int idx = t + i * 256;              // < 384 = 64 rows * 6 octets
    if (idx < 384) {
      int r = idx / 6, j = idx - r * 6;
      short8 vv = *(const short8*)(&vbf[((size_t)b * NTOK + chunk * 64 + r) * 384
                                        + h * HD + j * 8]);
      floatx4 f0, f1;
      #pragma unroll
      for (int kk = 0; kk < 4; kk++) {
        f0[kk] = bf2f((unsigned short)vv[kk]);
        f1[kk] = bf2f((unsigned short)vv[4 + kk]);
      }
      *(floatx4*)(&vs[r * 56 + j * 8]) = f0;
      *(floatx4*)(&vs[r * 56 + j * 8 + 4]) = f1;
    }
  }
  __syncthreads();
  floatx4 v4[12];
  #pragma unroll
  for (int j = 0; j < 12; j++)
    v4[j] = *(const floatx4*)(&vs[lane * 56 + j * 4]);
  float r[12];
  #pragma unroll
  for (int dd = 0; dd < 12; dd++) {
    int d = w * 12 + dd;
    floatx4 a = {};
    #pragma unroll
    for (int j = 0; j < 12; j++)
      a += *(const floatx4*)(&at[d * 52 + j * 4]) * v4[j];
    r[dd] = a[0] + a[1] + a[2] + a[3];
  }
  size_t wo = ((size_t)b * NTOK + chunk * 64 + lane) * DIM + h * HD + w * 12;
  unsigned int* op = (unsigned int*)(yat + wo);
  #pragma unroll
  for (int j = 0; j < 6; j++)
    op[j] = (unsigned int)f2bf(r[2 * j]) | ((unsigned int)f2bf(r[2 * j + 1]) << 16);
}

// ---------------------------------------------------------------------------
// Final transpose: [B,N,C] fp32 -> [B,C,N] fp32 (32x32 LDS tiles)
// ---------------------------------------------------------------------------
__global__ __launch_bounds__(256) void transpose_out(const float* __restrict__ in,
                                                     float* __restrict__ out) {
  __shared__ float tile[32][33];
  int b = blockIdx.z, ct = blockIdx.y, nt = blockIdx.x;
  int t = threadIdx.x;
  int cc = t & 31, rr = t >> 5;
  #pragma unroll
  for (int i = 0; i < 4; i++) {
    int nn = rr + i * 8;
    tile[nn][cc] = in[((size_t)b * NTOK + nt * 32 + nn) * DIM + ct * 32 + cc];
  }
  __syncthreads();
  #pragma unroll
  for (int i = 0; i < 4; i++) {
    int c2 = rr + i * 8;
    out[((size_t)b * DIM + ct * 32 + c2) * NTOK + nt * 32 + cc] = tile[cc][c2];
  }
}

// ---------------------------------------------------------------------------
extern "C" void kernel_launch(void* const* d_in, const int* in_sizes, int n_in,
                              void* d_out, int out_size, void* d_ws, size_t ws_size,
                              hipStream_t stream) {
  const float* x       = (const float*)d_in[0];
  const float* dw_w0   = (const float*)d_in[1];
  const float* dw_b0   = (const float*)d_in[2];
  const float* dw_w1   = (const float*)d_in[3];
  const float* dw_b1   = (const float*)d_in[4];
  const float* ln1_g   = (const float*)d_in[5];
  const float* ln1_b   = (const float*)d_in[6];
  const float* qkv_w   = (const float*)d_in[7];
  const float* proj_w  = (const float*)d_in[8];
  const float* proj_b  = (const float*)d_in[9];
  const float* ln2_g   = (const float*)d_in[10];
  const float* ln2_b   = (const float*)d_in[11];
  const float* mlp1_dw = (const float*)d_in[12];
  const float* mlp1_uw = (const float*)d_in[13];
  const float* mlp1_ub = (const float*)d_in[14];
  const float* mlp2_dw = (const float*)d_in[15];
  const float* mlp2_uw = (const float*)d_in[16];
  const float* mlp2_ub = (const float*)d_in[17];
  float* out = (float*)d_out;
  char* ws = (char*)d_ws;

  // ---- workspace layout, lifetime-aliased; peak 235,094,016 B (~224 MiB) ----
  float*          xflat = (float*)(ws + 0);                    // 77,070,336  alive 3-8
  float*          s1ws  = (float*)(ws + 77070336);             // 25,690,112  alive 1-3
  float*          s2ws  = (float*)(ws + 102760448);            // 25,690,112  alive 2-3
  unsigned short* vbf   = (unsigned short*)(ws + 77070336);    // 38,535,168  alive 4-7
  unsigned short* ybf   = (unsigned short*)(ws + 128450560);   // 38,535,168  alive 3-4
  unsigned short* ybfT  = (unsigned short*)(ws + 166985728);   // 38,535,168  alive 3-5a
  unsigned short* G_part= (unsigned short*)(ws + 128450560);   // 33,030,144  alive 5a-5b
  unsigned short* Gbf   = (unsigned short*)(ws + 205520896);   //  4,718,592  alive 5b-6a
  float*          P     = (float*)(ws + 210239488);            // 18,874,368  alive 6a-6b
  unsigned short* yat   = (unsigned short*)(ws + 166985728);   // 38,535,168  alive 7-8
  float*          xres  = (float*)(ws + 77070336);             // 77,070,336  alive 8-13
  unsigned short* zbf   = (unsigned short*)(ws + 0);           // 38,535,168  alive 9-10
  unsigned short* h1    = (unsigned short*)(ws + 38535168);    // 19,267,584  alive 10-11
  unsigned short* h3    = (unsigned short*)(ws + 57802752);    // 19,267,584  alive 11-12
  unsigned short* h2    = (unsigned short*)(ws + 154140672);   // 77,070,336  alive 11 (half-T)
  unsigned short* qkvT  = (unsigned short*)(ws + 231211008);   //    884,736
  unsigned short* projT = (unsigned short*)(ws + 232095744);   //    294,912
  unsigned short* m1dT  = (unsigned short*)(ws + 232390656);   //    147,456
  unsigned short* m1uT  = (unsigned short*)(ws + 232538112);   //    589,824
  unsigned short* m2dT  = (unsigned short*)(ws + 233127936);   //    589,824
  unsigned short* m2uT  = (unsigned short*)(ws + 233717760);   //    147,456
  float*          attnb = (float*)(ws + 233914368);            //  1,179,648 -> 235,094,016

  // weights -> [N,K] bf16
  wtrans<<<1728, 256, 0, stream>>>(qkv_w, qkvT, 384, 1152);
  wtrans<<<576, 256, 0, stream>>>(proj_w, projT, 384, 384);
  wtrans<<<288, 256, 0, stream>>>(mlp1_dw, m1dT, 384, 192);
  wtrans<<<1152, 256, 0, stream>>>(mlp1_uw, m1uT, 192, 1536);
  wtrans<<<1152, 256, 0, stream>>>(mlp2_dw, m2dT, 1536, 192);
  wtrans<<<288, 256, 0, stream>>>(mlp2_uw, m2uT, 192, 384);

  // depthwise chain: s1' = conv(s1+s0), s2' = conv(s2+s1')
  dwconv<<<25088, 256, 0, stream>>>(x + 128 * NTOK, (long)DIM * NTOK,
                                    x, (long)DIM * NTOK, dw_w0, dw_b0, s1ws);
  dwconv<<<25088, 256, 0, stream>>>(x + 256 * NTOK, (long)DIM * NTOK,
                                    s1ws, (long)128 * NTOK, dw_w1, dw_b1, s2ws);

  // (3) gather + LN1, emit y [T,384], yT [B,384,3136]
  build_ln1<<<1568, 256, 0, stream>>>(x, s1ws, s2ws, ln1_g, ln1_b, xflat, ybf, ybfT);

  // (4) V = y @ Wv   [T,384] bf16
  gemmx<128, 0><<<dim3(3, 392), 256, 0, stream>>>(
      ybf, qkvT + 768 * 384, nullptr, nullptr, vbf,
      TTOK, 384, 384, 384, 384, 1, 0, 0, 0, 0, 0);

  // (5a) G partials: G_part[b*7+s] = Yb[:,s-window]^T Yb[:,s-window]  (bf16)
  gemmx<128, 0><<<dim3(3, 3, 112), 256, 0, stream>>>(
      ybfT, ybfT, nullptr, nullptr, G_part,
      384, 384, 448, 3136, 3136, 7,
      (long)384 * 3136, 448L, (long)384 * 3136, 448L, 147456L);
  // (5b) sum 7 slabs -> Gbf
  gsum<<<9216, 256, 0, stream>>>(G_part, Gbf);

  // (6a) P = Wqk^T G   [768][384] fp32 per b
  gemmx<128, 3><<<dim3(3, 6, 16), 256, 0, stream>>>(
      qkvT, Gbf, nullptr, nullptr, P,
      768, 384, 384, 384, 384, 1,
      0, 0, 147456L, 0, 294912L);
  // (6b) S + norms + softmax -> attnb
  attn_finish2<<<NB * NH, 256, 0, stream>>>(P, qkvT, qkv_w, attnb);

  // (7) y_attn = attn @ v  -> bf16 [T,384]
  attn_apply<<<NB * NH * 49, 256, 0, stream>>>(vbf, attnb, yat);

  // (8) x_res = x_flat + y_attn @ proj_w + proj_b   (fp32)
  gemmx<128, 2><<<dim3(3, 392), 256, 0, stream>>>(
      yat, projT, proj_b, xflat, xres,
      TTOK, 384, 384, 384, 384, 1, 0, 0, 0, 0, 0);
  // (9) z = LN2(x_res)  bf16
  ln_rows<<<12544, 256, 0, stream>>>(xres, ln2_g, ln2_b, zbf);
  // (10) MLP down: h1 = z @ mlp1_dw  [T,192]
  gemmx<64, 0><<<dim3(3, 392), 256, 0, stream>>>(
      zbf, m1dT, nullptr, nullptr, h1,
      TTOK, 192, 384, 384, 384, 1, 0, 0, 0, 0, 0);
  // (11) MLP mid in two half-T passes through one 77MB h2 buffer (unfused)
  for (int half = 0; half < 2; half++) {
    const unsigned short* h1p = h1 + (size_t)half * 25088 * 192;
    unsigned short* h3p = h3 + (size_t)half * 25088 * 192;
    gemmx<128, 1><<<dim3(12, 196), 256, 0, stream>>>(
        h1p, m1uT, mlp1_ub, nullptr, h2,
        25088, 1536, 192, 192, 192, 1, 0, 0, 0, 0, 0);
    gemmx<64, 0><<<dim3(3, 196), 256, 0, stream>>>(
        h2, m2dT, nullptr, nullptr, h3p,
        25088, 192, 1536, 1536, 1536, 1, 0, 0, 0, 0, 0);
  }
  // (12) out_flat = x_res + h3 @ mlp2_uw + b   (in-place over x_res)
  gemmx<128, 2><<<dim3(3, 392), 256, 0, stream>>>(
      h3, m2uT, mlp2_ub, xres, xres,
      TTOK, 384, 192, 192, 192, 1, 0, 0, 0, 0, 0);
  // (13) [B,N,C] -> [B,C,H,W]
  transpose_out<<<dim3(98, 12, 16), 256, 0, stream>>>(xres, out);
}

// Round 9
// 797.352 us; speedup vs baseline: 1.0633x; 1.0633x over previous
//
#include <hip/hip_runtime.h>

// ---------------------------------------------------------------------------
// SDTA block on MI355X.  B=16, C=384, H=W=56, N=3136, T=B*N=50176, NH=8, HD=48
// XCA trick: S = Wq^T (Y^T Y) Wk  -> compute G=Y^T Y per batch (384x384), then
// P = Wqk^T G, S_h = Pq_h @ Wk_h, norms = diag(P . Wqk).
// MLP mid: UNFUSED two half-T passes through h2 (fused variants measured
// slower; rounds 4-6).  gemmx: single-buffer m97 loop (counted-vmcnt dbuf
// measured slower, round 8 -- reverted).
// Byte-reduction (this round): residual stream xres is bf16 (one extra
// rounding, xflat stays fp32), and the final GEMM writes fp32 directly to
// out[b][c][n] (MODE 4) -- the 154MB transpose_out pass is deleted.
// Workspace peak: 235,094,016 B (224.2 MiB) — lifetime-aliased regions.
// ---------------------------------------------------------------------------

typedef __attribute__((ext_vector_type(8))) short short8;
typedef __attribute__((ext_vector_type(4))) float floatx4;

#define NB 16
#define DIM 384
#define NTOK 3136
#define TTOK 50176   // NB*NTOK
#define NH 8
#define HD 48

__device__ __forceinline__ unsigned short f2bf(float f) {
  union { float f; unsigned int u; } v; v.f = f;
  unsigned int u = v.u;
  unsigned int r = (u + 0x7FFFu + ((u >> 16) & 1u)) >> 16;  // RNE
  return (unsigned short)r;
}
__device__ __forceinline__ float bf2f(unsigned short h) {
  union { unsigned int u; float f; } v; v.u = ((unsigned int)h) << 16;
  return v.f;
}

// async global->LDS, 16B per lane; LDS dest is wave-uniform base + lane*16.
__device__ __forceinline__ void gload_lds16(const unsigned short* g, unsigned short* l) {
  __builtin_amdgcn_global_load_lds(
      (const __attribute__((address_space(1))) unsigned int*)g,
      (__attribute__((address_space(3))) unsigned int*)l, 16, 0, 0);
}

// ---------------------------------------------------------------------------
// Weight transpose + bf16 convert:  wt[n*K+k] = bf16(w[k*N+n])
// ---------------------------------------------------------------------------
__global__ void wtrans(const float* __restrict__ w, unsigned short* __restrict__ wt,
                       int K, int N) {
  int g = blockIdx.x * 256 + threadIdx.x;
  if (g < K * N) {
    int k = g / N, n = g % N;
    wt[(size_t)n * K + k] = f2bf(w[g]);
  }
}

// ---------------------------------------------------------------------------
// Depthwise 3x3 conv, SAME, with two-source add: dst = conv(a+b) + bias
// ---------------------------------------------------------------------------
__global__ void dwconv(const float* __restrict__ a, long bsA,
                       const float* __restrict__ b2, long bsB,
                       const float* __restrict__ w, const float* __restrict__ bias,
                       float* __restrict__ dst) {
  int g = blockIdx.x * 256 + threadIdx.x;   // < 16*128*3136
  int xx = g % 56;
  int yy = (g / 56) % 56;
  int c  = (g / NTOK) % 128;
  int b  = g / (NTOK * 128);
  const float* pa = a  + (size_t)b * bsA + (size_t)c * NTOK;
  const float* pb = b2 + (size_t)b * bsB + (size_t)c * NTOK;
  float acc = bias[c];
  #pragma unroll
  for (int ky = 0; ky < 3; ky++) {
    int y2 = yy + ky - 1;
    if (y2 < 0 || y2 >= 56) continue;
    #pragma unroll
    for (int kx = 0; kx < 3; kx++) {
      int x2 = xx + kx - 1;
      if (x2 < 0 || x2 >= 56) continue;
      acc += w[c * 9 + ky * 3 + kx] * (pa[y2 * 56 + x2] + pb[y2 * 56 + x2]);
    }
  }
  dst[((size_t)b * 128 + c) * NTOK + yy * 56 + xx] = acc;
}

// ---------------------------------------------------------------------------
// build_ln1 (tiled): gather NCHW pieces for 32 tokens into a [384][33] fp32
// LDS tile, per-token LN, write x_flat fp32 [T,384], y bf16 [T,384], and
// yT bf16 [B,384,3136] (channel-major, for the G = Y^T Y gemm).
// ---------------------------------------------------------------------------
__global__ __launch_bounds__(256) void build_ln1(
    const float* __restrict__ x, const float* __restrict__ s1,
    const float* __restrict__ s2, const float* __restrict__ g,
    const float* __restrict__ bb, float* __restrict__ xflat,
    unsigned short* __restrict__ y, unsigned short* __restrict__ yT) {
  __shared__ float tile[384 * 33];
  __shared__ float psum[8][32], psumsq[8][32];
  __shared__ float smean[32], srs[32];
  int blk = blockIdx.x;
  int b = blk / 98, n0 = (blk % 98) * 32;
  int t = threadIdx.x;
  int nl = t & 31, crow = t >> 5;        // staging: lane->n (coalesced), 8 c-rows/iter

  #pragma unroll 4
  for (int i = 0; i < 48; i++) {
    int c = i * 8 + crow;
    float v;
    if (c < 128)      v = x[((size_t)b * DIM + c) * NTOK + n0 + nl];
    else if (c < 256) v = s1[((size_t)b * 128 + (c - 128)) * NTOK + n0 + nl];
    else              v = s2[((size_t)b * 128 + (c - 256)) * NTOK + n0 + nl];
    tile[c * 33 + nl] = v;
  }
  __syncthreads();

  // per-token partial sums: 8 segments of 48 channels
  {
    int seg = t >> 5, tok = t & 31;
    float s = 0.f, sq = 0.f;
    #pragma unroll 8
    for (int cc = 0; cc < 48; cc++) {
      float v = tile[(seg * 48 + cc) * 33 + tok];
      s += v; sq += v * v;
    }
    psum[seg][tok] = s; psumsq[seg][tok] = sq;
  }
  __syncthreads();
  if (t < 32) {
    float s = 0.f, sq = 0.f;
    #pragma unroll
    for (int seg = 0; seg < 8; seg++) { s += psum[seg][t]; sq += psumsq[seg][t]; }
    float mean = s * (1.f / DIM);
    float var = sq * (1.f / DIM) - mean * mean;
    smean[t] = mean;
    srs[t] = rsqrtf(var + 1e-6f);
  }
  __syncthreads();

  // output: coalesced rows of x_flat / y; overwrite tile with normalized vals
  #pragma unroll 4
  for (int i = 0; i < 48; i++) {
    int idx = i * 256 + t;               // < 12288 = 32*384
    int tok = idx / 384, c = idx - tok * 384;
    float v = tile[c * 33 + tok];
    float vn = (v - smean[tok]) * srs[tok] * g[c] + bb[c];
    size_t o = (size_t)(b * NTOK + n0 + tok) * DIM + c;
    xflat[o] = v;
    y[o] = f2bf(vn);
    tile[c * 33 + tok] = vn;             // slot (c,tok) touched by this thread only
  }
  __syncthreads();
  // transposed write: yT[b][c][n]
  #pragma unroll 4
  for (int i = 0; i < 48; i++) {
    int idx = i * 256 + t;
    int c = idx >> 5, tok = idx & 31;
    yT[((size_t)b * DIM + c) * NTOK + n0 + tok] = f2bf(tile[c * 33 + tok]);
  }
}

// ---------------------------------------------------------------------------
// Plain rowwise LN: bf16 [T,384] -> bf16 [T,384]
// ---------------------------------------------------------------------------
__global__ __launch_bounds__(256) void ln_rows(
    const unsigned short* __restrict__ in, const float* __restrict__ g,
    const float* __restrict__ bb, unsigned short* __restrict__ out) {
  int tkn = blockIdx.x * 4 + (threadIdx.x >> 6);
  int lane = threadIdx.x & 63;
  const unsigned short* row = in + (size_t)tkn * DIM;
  float v[6];
  float s = 0.f, sq = 0.f;
  #pragma unroll
  for (int i = 0; i < 6; i++) {
    int c = lane + i * 64;
    v[i] = bf2f(row[c]); s += v[i]; sq += v[i] * v[i];
  }
  #pragma unroll
  for (int off = 32; off; off >>= 1) {
    s += __shfl_xor(s, off);
    sq += __shfl_xor(sq, off);
  }
  float mean = s * (1.f / DIM);
  float var = sq * (1.f / DIM) - mean * mean;
  float rs = rsqrtf(var + 1e-6f);
  #pragma unroll
  for (int i = 0; i < 6; i++) {
    int c = lane + i * 64;
    out[(size_t)tkn * DIM + c] = f2bf((v[i] - mean) * rs * g[c] + bb[c]);
  }
}

// ---------------------------------------------------------------------------
// 128-tile MFMA GEMM (m97 structure): C[M,N] = A[M,K] @ Bt[N,K]^T, bf16 in.
// MODE 0: bf16 out | MODE 1: +bias, exact GELU, bf16 | MODE 2: +bias+fp32
// resid -> bf16 out | MODE 3: plain fp32 out | MODE 4: +bias+bf16 resid ->
// fp32 out written TRANSPOSED to [B,DIM,NTOK] (fuses the output transpose;
// 4 acc p-values = 4 consecutive n -> aligned float4 store).
// Generalized: lda/ldb row strides, blockIdx.z batching with optional K-split,
// T1 bijective XCD-aware (x,y) swizzle (m204).
// ---------------------------------------------------------------------------
template<int BN, int MODE>
__global__ __launch_bounds__(256) void gemmx(
    const unsigned short* __restrict__ A, const unsigned short* __restrict__ Bt,
    const float* __restrict__ bias, const void* __restrict__ resid,
    void* __restrict__ out, int M, int N, int K, int lda, int ldb,
    int nsplit, long aBatch, long aSplit, long bBatch, long bSplit, long cBatch) {
  constexpr int MT = (BN == 128) ? 4 : 2;
  constexpr int NT = 4;
  __shared__ __align__(16) unsigned short As[128 * 32];
  __shared__ __align__(16) unsigned short Bs[BN * 32];
  const int tid = threadIdx.x;
  const int w = tid >> 6, lane = tid & 63;
  const int quad = lane >> 4, r16 = lane & 15;

  // bijective XCD swizzle over (x,y)
  const int nwg = gridDim.x * gridDim.y;
  const int bid = blockIdx.y * gridDim.x + blockIdx.x;
  const int q8 = nwg >> 3, r8 = nwg & 7;
  const int xcd = bid & 7, loc = bid >> 3;
  const int swz = (xcd < r8 ? xcd * (q8 + 1) : r8 * (q8 + 1) + (xcd - r8) * q8) + loc;
  const int bx = swz % gridDim.x, by = swz / gridDim.x;
  const int row0 = by * 128, col0 = bx * BN;

  const int z = blockIdx.z;
  const int bz = z / nsplit, sz = z - bz * nsplit;
  A  += bz * aBatch + sz * aSplit;
  Bt += bz * bBatch + sz * bSplit;
  const size_t cOff = (size_t)z * cBatch;

  const int wm = (BN == 128) ? (w >> 1) * 64 : w * 32;
  const int wn = (BN == 128) ? (w & 1) * 64 : 0;
  const int lrow = lane >> 2;
  const int lcol = (lane & 3) * 8;

  const unsigned short* aP0 = A + (size_t)(row0 + w * 32 + lrow) * lda + lcol;
  const unsigned short* aP1 = aP0 + (size_t)16 * lda;
  const unsigned short* bP0 = Bt + (size_t)(col0 + ((BN == 128) ? w * 32 : w * 16) + lrow) * ldb + lcol;
  const unsigned short* bP1 = bP0 + (size_t)16 * ldb;

  floatx4 acc[MT][NT] = {};

  for (int k0 = 0; k0 < K; k0 += 32) {
    gload_lds16(aP0 + k0, &As[(2 * w) * 512]);
    gload_lds16(aP1 + k0, &As[(2 * w + 1) * 512]);
    if (BN == 128) {
      gload_lds16(bP0 + k0, &Bs[(2 * w) * 512]);
      gload_lds16(bP1 + k0, &Bs[(2 * w + 1) * 512]);
    } else {
      gload_lds16(bP0 + k0, &Bs[w * 512]);
    }
    __syncthreads();
    short8 af[MT], bfr[NT];
    #pragma unroll
    for (int mi = 0; mi < MT; mi++)
      af[mi] = *(const short8*)(&As[(wm + mi * 16 + r16) * 32 + quad * 8]);
    #pragma unroll
    for (int ni = 0; ni < NT; ni++)
      bfr[ni] = *(const short8*)(&Bs[(wn + ni * 16 + r16) * 32 + quad * 8]);
    #pragma unroll
    for (int mi = 0; mi < MT; mi++)
      #pragma unroll
      for (int ni = 0; ni < NT; ni++)
        acc[mi][ni] = __builtin_amdgcn_mfma_f32_16x16x32_bf16(af[mi], bfr[ni], acc[mi][ni], 0, 0, 0);
    __syncthreads();
  }

  #pragma unroll
  for (int mi = 0; mi < MT; mi++)
    #pragma unroll
    for (int ni = 0; ni < NT; ni++) {
      if (MODE == 4) {
        // transposed fp32 store: out[b][col][n], 4 consecutive n per thread
        int r0 = row0 + wm + mi * 16 + quad * 4;
        int col = col0 + wn + ni * 16 + r16;
        int bq = r0 / NTOK, nn = r0 - bq * NTOK;   // 4-row span stays in-batch
        floatx4 vv;
        #pragma unroll
        for (int p = 0; p < 4; p++)
          vv[p] = acc[mi][ni][p] + bias[col] +
                  bf2f(((const unsigned short*)resid)[(size_t)(r0 + p) * N + col]);
        *(floatx4*)&((float*)out)[((size_t)bq * DIM + col) * NTOK + nn] = vv;
      } else {
        #pragma unroll
        for (int p = 0; p < 4; p++) {
          int row = row0 + wm + mi * 16 + quad * 4 + p;
          int col = col0 + wn + ni * 16 + r16;
          size_t idx = (size_t)row * N + col;
          float v = acc[mi][ni][p];
          if (MODE == 0) {
            ((unsigned short*)out)[cOff + idx] = f2bf(v);
          } else if (MODE == 1) {
            v += bias[col];
            v = 0.5f * v * (1.0f + erff(v * 0.70710678118654752f));
            ((unsigned short*)out)[idx] = f2bf(v);
          } else if (MODE == 2) {
            v += bias[col] + ((const float*)resid)[idx];
            ((unsigned short*)out)[idx] = f2bf(v);
          } else {
            ((float*)out)[cOff + idx] = v;
          }
        }
      }
    }
}

// ---------------------------------------------------------------------------
// Sum the 7 K-split G partial slabs (bf16) -> Gbf [16][384*384] bf16.
// ---------------------------------------------------------------------------
__global__ __launch_bounds__(256) void gsum(const unsigned short* __restrict__ Gp,
                                            unsigned short* __restrict__ Gbf) {
  int b = blockIdx.x / 576;                         // 576 blocks per batch
  int i = (blockIdx.x % 576) * 256 + threadIdx.x;   // < 147456
  float s = 0.f;
  #pragma unroll
  for (int p = 0; p < 7; p++)
    s += bf2f(Gp[((size_t)(b * 7 + p)) * 147456 + i]);
  Gbf[(size_t)b * 147456 + i] = f2bf(s);
}

// ---------------------------------------------------------------------------
// attn_finish2: per (b,h) block.  P = Wqk^T G  ([768][384] fp32 per b).
//   S[d][e]  = sum_c Pq[h*48+d][c] * Wk[c][h*48+e]   (Wk staged bf16 from qkvT)
//   nq[d]    = sum_c Pq[h*48+d][c] * Wq[c][h*48+d]   (fp32 qkv_w column)
//   nk[e]    = sum_c Pk[384+h*48+e][c] * Wk[c][h*48+e]
// then row softmax of S/(qn*kn) -> attnb[bh][48][48].
// ---------------------------------------------------------------------------
__global__ __launch_bounds__(256) void attn_finish2(
    const float* __restrict__ P, const unsigned short* __restrict__ qkvT,
    const float* __restrict__ qkv_w, float* __restrict__ attnb) {
  __shared__ unsigned short wkT[48 * 392];   // wkT[e][c] bf16
  __shared__ float Ss[48 * 49];
  __shared__ float qn[48], kn[48];
  int bh = blockIdx.x, b = bh >> 3, h = bh & 7;
  int t = threadIdx.x;
  const float* Pb = P + (size_t)b * 294912;

  // stage Wk_h^T rows (qkvT rows 384+h*48 .. +48, each 384 bf16)
  #pragma unroll
  for (int i = 0; i < 9; i++) {
    int idx = t + i * 256;                   // < 2304 = 48 rows * 48 chunks
    int e = idx / 48, j = idx - e * 48;
    *(short8*)(&wkT[e * 392 + j * 8]) =
        *(const short8*)(&qkvT[(size_t)(384 + h * 48 + e) * 384 + j * 8]);
  }
  // norms (waves 0 and 1 partial-idle; cheap)
  if (t < 48) {
    const float* pr = Pb + (size_t)(h * 48 + t) * 384;
    const float* wc = qkv_w + h * 48 + t;
    float s = 0.f;
    #pragma unroll 8
    for (int c = 0; c < 384; c++) s += pr[c] * wc[(size_t)c * 1152];
    qn[t] = fmaxf(sqrtf(fmaxf(s, 0.f)), 1e-12f);
  } else if (t >= 64 && t < 112) {
    int e = t - 64;
    const float* pr = Pb + (size_t)(384 + h * 48 + e) * 384;
    const float* wc = qkv_w + 384 + h * 48 + e;
    float s = 0.f;
    #pragma unroll 8
    for (int c = 0; c < 384; c++) s += pr[c] * wc[(size_t)c * 1152];
    kn[e] = fmaxf(sqrtf(fmaxf(s, 0.f)), 1e-12f);
  }
  __syncthreads();

  // S: thread owns 3x3 of the 48x48 output
  int d0 = (t >> 4) * 3, e0 = (t & 15) * 3;
  float acc[3][3] = {};
  const float* pq0 = Pb + (size_t)(h * 48 + d0) * 384;
  for (int c8 = 0; c8 < 48; c8++) {
    floatx4 pv[3][2];
    #pragma unroll
    for (int i = 0; i < 3; i++) {
      pv[i][0] = *(const floatx4*)(pq0 + (size_t)i * 384 + c8 * 8);
      pv[i][1] = *(const floatx4*)(pq0 + (size_t)i * 384 + c8 * 8 + 4);
    }
    #pragma unroll
    for (int j = 0; j < 3; j++) {
      short8 wv = *(const short8*)(&wkT[(e0 + j) * 392 + c8 * 8]);
      #pragma unroll
      for (int kk = 0; kk < 4; kk++) {
        float wa = bf2f((unsigned short)wv[kk]);
        float wb = bf2f((unsigned short)wv[4 + kk]);
        #pragma unroll
        for (int i = 0; i < 3; i++)
          acc[i][j] += pv[i][0][kk] * wa + pv[i][1][kk] * wb;
      }
    }
  }
  #pragma unroll
  for (int i = 0; i < 3; i++)
    #pragma unroll
    for (int j = 0; j < 3; j++)
      Ss[(d0 + i) * 49 + e0 + j] = acc[i][j] / (qn[d0 + i] * kn[e0 + j]);
  __syncthreads();

  if (t < 48) {
    float m = -1e30f;
    for (int e = 0; e < 48; e++) m = fmaxf(m, Ss[t * 49 + e]);
    float ssum = 0.f;
    float ex[48];
    for (int e = 0; e < 48; e++) { ex[e] = expf(Ss[t * 49 + e] - m); ssum += ex[e]; }
    float inv = 1.f / ssum;
    float* op = attnb + (size_t)bh * 2304 + t * 48;
    for (int e = 0; e < 48; e++) op[e] = ex[e] * inv;
  }
}

// ---------------------------------------------------------------------------
// y_attn[b,n,h*48+d] = sum_e attn[b,h,d,e] * v[b,n,h,e]   -> bf16
// 6272 blocks = (b,h,chunk-of-64).  V comes from vbf [T,384] bf16.
// ---------------------------------------------------------------------------
__global__ __launch_bounds__(256) void attn_apply(
    const unsigned short* __restrict__ vbf, const float* __restrict__ attnb,
    unsigned short* __restrict__ yat) {
  __shared__ float at[48 * 52];
  __shared__ float vs[64 * 56];
  int bh = blockIdx.x / 49, chunk = blockIdx.x % 49;
  int b = bh >> 3, h = bh & 7;
  int t = threadIdx.x;
  int lane = t & 63, w = t >> 6;
  #pragma unroll
  for (int i = 0; i < 9; i++) {
    int idx = t + i * 256;
    if (idx < 2304) at[(idx / 48) * 52 + idx % 48] = attnb[(size_t)bh * 2304 + idx];
  }
  #pragma unroll
  for (int i = 0; i < 2; i++) {
    int idx = t + i * 256;              // < 384 = 64 rows * 6 octets
    if (idx < 384) {
      int r = idx / 6, j = idx - r * 6;
      short8 vv = *(const short8*)(&vbf[((size_t)b * NTOK + chunk * 64 + r) * 384
                                        + h * HD + j * 8]);
      floatx4 f0, f1;
      #pragma unroll
      for (int kk = 0; kk < 4; kk++) {
        f0[kk] = bf2f((unsigned short)vv[kk]);
        f1[kk] = bf2f((unsigned short)vv[4 + kk]);
      }
      *(floatx4*)(&vs[r * 56 + j * 8]) = f0;
      *(floatx4*)(&vs[r * 56 + j * 8 + 4]) = f1;
    }
  }
  __syncthreads();
  floatx4 v4[12];
  #pragma unroll
  for (int j = 0; j < 12; j++)
    v4[j] = *(const floatx4*)(&vs[lane * 56 + j * 4]);
  float r[12];
  #pragma unroll
  for (int dd = 0; dd < 12; dd++) {
    int d = w * 12 + dd;
    floatx4 a = {};
    #pragma unroll
    for (int j = 0; j < 12; j++)
      a += *(const floatx4*)(&at[d * 52 + j * 4]) * v4[j];
    r[dd] = a[0] + a[1] + a[2] + a[3];
  }
  size_t wo = ((size_t)b * NTOK + chunk * 64 + lane) * DIM + h * HD + w * 12;
  unsigned int* op = (unsigned int*)(yat + wo);
  #pragma unroll
  for (int j = 0; j < 6; j++)
    op[j] = (unsigned int)f2bf(r[2 * j]) | ((unsigned int)f2bf(r[2 * j + 1]) << 16);
}

// ---------------------------------------------------------------------------
extern "C" void kernel_launch(void* const* d_in, const int* in_sizes, int n_in,
                              void* d_out, int out_size, void* d_ws, size_t ws_size,
                              hipStream_t stream) {
  const float* x       = (const float*)d_in[0];
  const float* dw_w0   = (const float*)d_in[1];
  const float* dw_b0   = (const float*)d_in[2];
  const float* dw_w1   = (const float*)d_in[3];
  const float* dw_b1   = (const float*)d_in[4];
  const float* ln1_g   = (const float*)d_in[5];
  const float* ln1_b   = (const float*)d_in[6];
  const float* qkv_w   = (const float*)d_in[7];
  const float* proj_w  = (const float*)d_in[8];
  const float* proj_b  = (const float*)d_in[9];
  const float* ln2_g   = (const float*)d_in[10];
  const float* ln2_b   = (const float*)d_in[11];
  const float* mlp1_dw = (const float*)d_in[12];
  const float* mlp1_uw = (const float*)d_in[13];
  const float* mlp1_ub = (const float*)d_in[14];
  const float* mlp2_dw = (const float*)d_in[15];
  const float* mlp2_uw = (const float*)d_in[16];
  const float* mlp2_ub = (const float*)d_in[17];
  float* out = (float*)d_out;
  char* ws = (char*)d_ws;

  // ---- workspace layout, lifetime-aliased; peak 235,094,016 B (~224 MiB) ----
  float*          xflat = (float*)(ws + 0);                    // 77,070,336  alive 3-8
  float*          s1ws  = (float*)(ws + 77070336);             // 25,690,112  alive 1-3
  float*          s2ws  = (float*)(ws + 102760448);            // 25,690,112  alive 2-3
  unsigned short* vbf   = (unsigned short*)(ws + 77070336);    // 38,535,168  alive 4-7
  unsigned short* ybf   = (unsigned short*)(ws + 128450560);   // 38,535,168  alive 3-4
  unsigned short* ybfT  = (unsigned short*)(ws + 166985728);   // 38,535,168  alive 3-5a
  unsigned short* G_part= (unsigned short*)(ws + 128450560);   // 33,030,144  alive 5a-5b
  unsigned short* Gbf   = (unsigned short*)(ws + 205520896);   //  4,718,592  alive 5b-6a
  float*          P     = (float*)(ws + 210239488);            // 18,874,368  alive 6a-6b
  unsigned short* yat   = (unsigned short*)(ws + 166985728);   // 38,535,168  alive 7-8
  unsigned short* xres  = (unsigned short*)(ws + 77070336);    // 38,535,168  alive 8-12 (bf16)
  unsigned short* zbf   = (unsigned short*)(ws + 0);           // 38,535,168  alive 9-10
  unsigned short* h1    = (unsigned short*)(ws + 38535168);    // 19,267,584  alive 10-11
  unsigned short* h3    = (unsigned short*)(ws + 57802752);    // 19,267,584  alive 11-12
  unsigned short* h2    = (unsigned short*)(ws + 154140672);   // 77,070,336  alive 11 (half-T)
  unsigned short* qkvT  = (unsigned short*)(ws + 231211008);   //    884,736
  unsigned short* projT = (unsigned short*)(ws + 232095744);   //    294,912
  unsigned short* m1dT  = (unsigned short*)(ws + 232390656);   //    147,456
  unsigned short* m1uT  = (unsigned short*)(ws + 232538112);   //    589,824
  unsigned short* m2dT  = (unsigned short*)(ws + 233127936);   //    589,824
  unsigned short* m2uT  = (unsigned short*)(ws + 233717760);   //    147,456
  float*          attnb = (float*)(ws + 233914368);            //  1,179,648 -> 235,094,016

  // weights -> [N,K] bf16
  wtrans<<<1728, 256, 0, stream>>>(qkv_w, qkvT, 384, 1152);
  wtrans<<<576, 256, 0, stream>>>(proj_w, projT, 384, 384);
  wtrans<<<288, 256, 0, stream>>>(mlp1_dw, m1dT, 384, 192);
  wtrans<<<1152, 256, 0, stream>>>(mlp1_uw, m1uT, 192, 1536);
  wtrans<<<1152, 256, 0, stream>>>(mlp2_dw, m2dT, 1536, 192);
  wtrans<<<288, 256, 0, stream>>>(mlp2_uw, m2uT, 192, 384);

  // depthwise chain: s1' = conv(s1+s0), s2' = conv(s2+s1')
  dwconv<<<25088, 256, 0, stream>>>(x + 128 * NTOK, (long)DIM * NTOK,
                                    x, (long)DIM * NTOK, dw_w0, dw_b0, s1ws);
  dwconv<<<25088, 256, 0, stream>>>(x + 256 * NTOK, (long)DIM * NTOK,
                                    s1ws, (long)128 * NTOK, dw_w1, dw_b1, s2ws);

  // (3) gather + LN1, emit y [T,384], yT [B,384,3136]
  build_ln1<<<1568, 256, 0, stream>>>(x, s1ws, s2ws, ln1_g, ln1_b, xflat, ybf, ybfT);

  // (4) V = y @ Wv   [T,384] bf16
  gemmx<128, 0><<<dim3(3, 392), 256, 0, stream>>>(
      ybf, qkvT + 768 * 384, nullptr, nullptr, vbf,
      TTOK, 384, 384, 384, 384, 1, 0, 0, 0, 0, 0);

  // (5a) G partials: G_part[b*7+s] = Yb[:,s-window]^T Yb[:,s-window]  (bf16)
  gemmx<128, 0><<<dim3(3, 3, 112), 256, 0, stream>>>(
      ybfT, ybfT, nullptr, nullptr, G_part,
      384, 384, 448, 3136, 3136, 7,
      (long)384 * 3136, 448L, (long)384 * 3136, 448L, 147456L);
  // (5b) sum 7 slabs -> Gbf
  gsum<<<9216, 256, 0, stream>>>(G_part, Gbf);

  // (6a) P = Wqk^T G   [768][384] fp32 per b
  gemmx<128, 3><<<dim3(3, 6, 16), 256, 0, stream>>>(
      qkvT, Gbf, nullptr, nullptr, P,
      768, 384, 384, 384, 384, 1,
      0, 0, 147456L, 0, 294912L);
  // (6b) S + norms + softmax -> attnb
  attn_finish2<<<NB * NH, 256, 0, stream>>>(P, qkvT, qkv_w, attnb);

  // (7) y_attn = attn @ v  -> bf16 [T,384]
  attn_apply<<<NB * NH * 49, 256, 0, stream>>>(vbf, attnb, yat);

  // (8) x_res = x_flat + y_attn @ proj_w + proj_b   (bf16 residual stream)
  gemmx<128, 2><<<dim3(3, 392), 256, 0, stream>>>(
      yat, projT, proj_b, xflat, xres,
      TTOK, 384, 384, 384, 384, 1, 0, 0, 0, 0, 0);
  // (9) z = LN2(x_res)  bf16
  ln_rows<<<12544, 256, 0, stream>>>(xres, ln2_g, ln2_b, zbf);
  // (10) MLP down: h1 = z @ mlp1_dw  [T,192]
  gemmx<64, 0><<<dim3(3, 392), 256, 0, stream>>>(
      zbf, m1dT, nullptr, nullptr, h1,
      TTOK, 192, 384, 384, 384, 1, 0, 0, 0, 0, 0);
  // (11) MLP mid in two half-T passes through one 77MB h2 buffer (unfused)
  for (int half = 0; half < 2; half++) {
    const unsigned short* h1p = h1 + (size_t)half * 25088 * 192;
    unsigned short* h3p = h3 + (size_t)half * 25088 * 192;
    gemmx<128, 1><<<dim3(12, 196), 256, 0, stream>>>(
        h1p, m1uT, mlp1_ub, nullptr, h2,
        25088, 1536, 192, 192, 192, 1, 0, 0, 0, 0, 0);
    gemmx<64, 0><<<dim3(3, 196), 256, 0, stream>>>(
        h2, m2dT, nullptr, nullptr, h3p,
        25088, 192, 1536, 1536, 1536, 1, 0, 0, 0, 0, 0);
  }
  // (12) out[b][c][n] = x_res + h3 @ mlp2_uw + b  (fused transpose, fp32)
  gemmx<128, 4><<<dim3(3, 392), 256, 0, stream>>>(
      h3, m2uT, mlp2_ub, xres, out,
      TTOK, 384, 192, 192, 192, 1, 0, 0, 0, 0, 0);
}